// Round 2
// baseline (510.337 us; speedup 1.0000x reference)
//
#include <hip/hip_runtime.h>
#include <hip/hip_bf16.h>
#include <math.h>

// Problem constants
#define BB 64
#define TT 4096
#define DD 256
#define UU 256
#define CHUNKS 32         // chunks per batch -> grid 2048 blocks
#define TCHUNK 128        // TT / CHUNKS
#define MT 64             // timestep tile per iteration
#define NTILES 2          // TCHUNK / MT
#define LDA 264           // padded LDS row stride in bf16 elems (+8 pad)

typedef __attribute__((ext_vector_type(8))) short bf16x8;
typedef __attribute__((ext_vector_type(4))) float f32x4;

static __device__ __forceinline__ short f2bf(float f){
  unsigned u = __float_as_uint(f);
  u = (u + 0x7fffu + ((u >> 16) & 1u)) >> 16;   // RNE
  return (short)u;
}

// Kernel 0: W[d][u] fp32 -> Wt[u][d] bf16 (B-operand friendly layout)
__global__ void wconv_kernel(const float* __restrict__ W, short* __restrict__ Wt){
  int u = blockIdx.x;
  int d = threadIdx.x;
  Wt[u*DD + d] = f2bf(W[d*UU + u]);
}

// Kernel 1: flash-style fused logits + online softmax + weighted sum (per chunk)
__global__ __launch_bounds__(256)
void attn_main_kernel(const float* __restrict__ X, const short* __restrict__ Wt,
                      const float* __restrict__ Wb, const float* __restrict__ Vw,
                      float* __restrict__ m_part, float* __restrict__ l_part,
                      float* __restrict__ ctx_part)
{
  __shared__ short a_tile[MT*LDA];   // 33792 B bf16 X tile
  __shared__ float s_part[4][MT];    // per-wave logit partials (no atomics)
  __shared__ float s_pw[4][MT];      // per-wave p broadcast (same-wave RAW, no barrier)

  const int tid  = threadIdx.x;
  const int lane = tid & 63;
  const int wv   = tid >> 6;          // 4 waves, each owns 64 units
  const int b      = blockIdx.x >> 5; // / CHUNKS
  const int cchunk = blockIdx.x & 31;
  const int lo   = lane & 15;
  const int quad = lane >> 4;
  const int u_base = wv*64 + lo;

  float wb_r[4], v_r[4];
  #pragma unroll
  for (int nf=0; nf<4; ++nf){
    wb_r[nf] = Wb[u_base + nf*16];
    v_r[nf]  = Vw[u_base + nf*16];
  }

  // wave-private online-softmax state (lane-uniform, identical across waves)
  float m_run = -INFINITY;
  float l_run = 0.f;
  float ctx   = 0.f;
  const size_t x_chunk = ((size_t)b*TT + (size_t)cchunk*TCHUNK) * DD;

  for (int tile=0; tile<NTILES; ++tile){
    __syncthreads();   // protect a_tile (prev ctx reads) & s_part before overwrite
    const int t0 = tile*MT;

    // ---- stage: 64x256 fp32 -> bf16 LDS tile ----
    #pragma unroll
    for (int p8=0; p8<8; ++p8){
      int e   = p8*256 + tid;        // 8-float unit index, coalesced across lanes
      int row = e >> 5;              // 32 units per row
      int col = (e & 31) * 8;
      const float4* src = reinterpret_cast<const float4*>(
          X + x_chunk + (size_t)(t0+row)*DD + col);
      float4 x0 = src[0];
      float4 x1 = src[1];
      bf16x8 v;
      v[0]=f2bf(x0.x); v[1]=f2bf(x0.y); v[2]=f2bf(x0.z); v[3]=f2bf(x0.w);
      v[4]=f2bf(x1.x); v[5]=f2bf(x1.y); v[6]=f2bf(x1.z); v[7]=f2bf(x1.w);
      *reinterpret_cast<bf16x8*>(&a_tile[row*LDA + col]) = v;
    }
    __syncthreads();

    // ---- MFMA: score[64 x 64units] per wave, K=256 ----
    f32x4 acc[4][4];
    #pragma unroll
    for (int mf=0; mf<4; ++mf)
      #pragma unroll
      for (int nf=0; nf<4; ++nf)
        acc[mf][nf] = (f32x4){0.f,0.f,0.f,0.f};

    #pragma unroll
    for (int kt=0; kt<8; ++kt){
      const int k0 = kt*32 + quad*8;
      bf16x8 af[4];
      #pragma unroll
      for (int mf=0; mf<4; ++mf)
        af[mf] = *reinterpret_cast<const bf16x8*>(&a_tile[(mf*16 + lo)*LDA + k0]);
      #pragma unroll
      for (int nf=0; nf<4; ++nf){
        bf16x8 bfv = *reinterpret_cast<const bf16x8*>(&Wt[(size_t)(u_base + nf*16)*DD + k0]);
        #pragma unroll
        for (int mf=0; mf<4; ++mf)
          acc[mf][nf] = __builtin_amdgcn_mfma_f32_16x16x32_bf16(af[mf], bfv, acc[mf][nf], 0, 0, 0);
      }
    }

    // ---- epilogue: tanh, dot with V, reduce over this wave's 64 units ----
    // C/D layout: col(u)=lane&15, row(t)=quad*4+reg
    #pragma unroll
    for (int mf=0; mf<4; ++mf){
      #pragma unroll
      for (int r=0; r<4; ++r){
        float part = 0.f;
        #pragma unroll
        for (int nf=0; nf<4; ++nf){
          float s  = acc[mf][nf][r] + wb_r[nf];
          float e2 = __expf(2.f*s);
          float th = 1.f - 2.f/(e2 + 1.f);     // robust tanh: saturates at +/-1
          part = fmaf(th, v_r[nf], part);
        }
        part += __shfl_xor(part, 1);   // within 16-lane row -> DPP
        part += __shfl_xor(part, 2);
        part += __shfl_xor(part, 4);
        part += __shfl_xor(part, 8);
        if (lo == 0) s_part[wv][mf*16 + quad*4 + r] = part;
      }
    }
    __syncthreads();

    // ---- per-wave redundant online softmax (no further block syncs) ----
    float lt = s_part[0][lane] + s_part[1][lane] + s_part[2][lane] + s_part[3][lane];
    float mx = lt;
    #pragma unroll
    for (int o=32; o; o>>=1) mx = fmaxf(mx, __shfl_xor(mx, o));
    float m_new = fmaxf(m_run, mx);
    float p = __expf(lt - m_new);
    float sum = p;
    #pragma unroll
    for (int o=32; o; o>>=1) sum += __shfl_xor(sum, o);
    float alpha = __expf(m_run - m_new);   // exp(-inf)=0 handles first tile
    l_run = l_run * alpha + sum;
    m_run = m_new;
    s_pw[wv][lane] = p;                    // same-wave producer/consumer

    // ---- ctx update from bf16 LDS tile: thread d=tid sums p[t]*Xbf[t][d] ----
    ctx *= alpha;
    #pragma unroll
    for (int t2=0; t2<MT; ++t2){
      float pt = s_pw[wv][t2];             // LDS broadcast (same address per wave)
      unsigned xb = (unsigned short)a_tile[t2*LDA + tid];
      float xv = __uint_as_float(xb << 16);
      ctx = fmaf(pt, xv, ctx);
    }
  }

  const int pidx = blockIdx.x;
  if (tid == 0){ m_part[pidx] = m_run; l_part[pidx] = l_run; }
  ctx_part[(size_t)pidx*DD + tid] = ctx;
}

// Kernel 2: merge chunk partials per batch
__global__ void merge_kernel(const float* __restrict__ m_part, const float* __restrict__ l_part,
                             const float* __restrict__ ctx_part, float* __restrict__ out)
{
  int b = blockIdx.x;
  int d = threadIdx.x;
  float mg = -INFINITY;
  #pragma unroll
  for (int c=0; c<CHUNKS; ++c) mg = fmaxf(mg, m_part[b*CHUNKS+c]);
  float lg = 0.f, s = 0.f;
  #pragma unroll
  for (int c=0; c<CHUNKS; ++c){
    float w = __expf(m_part[b*CHUNKS+c] - mg);
    lg += l_part[b*CHUNKS+c] * w;
    s  += ctx_part[(size_t)(b*CHUNKS+c)*DD + d] * w;
  }
  out[b*DD + d] = s / lg;
}

extern "C" void kernel_launch(void* const* d_in, const int* in_sizes, int n_in,
                              void* d_out, int out_size, void* d_ws, size_t ws_size,
                              hipStream_t stream)
{
  const float* X  = (const float*)d_in[0];
  const float* Ww = (const float*)d_in[1];
  const float* Wb = (const float*)d_in[2];
  const float* Vw = (const float*)d_in[3];
  // V_b (d_in[4]) shifts all logits equally -> cancels in softmax; ignored.
  float* out = (float*)d_out;

  // workspace: Wt bf16 (128 KB) | m (2048 f) | l (2048 f) | ctx (2048*256 f)
  short* Wt       = (short*)d_ws;
  float* m_part   = (float*)((char*)d_ws + (size_t)UU*DD*sizeof(short));
  float* l_part   = m_part + BB*CHUNKS;
  float* ctx_part = l_part + BB*CHUNKS;

  wconv_kernel<<<UU, DD, 0, stream>>>(Ww, Wt);
  attn_main_kernel<<<BB*CHUNKS, 256, 0, stream>>>(X, Wt, Wb, Vw, m_part, l_part, ctx_part);
  merge_kernel<<<BB, DD, 0, stream>>>(m_part, l_part, ctx_part, out);
}

// Round 3
// 490.855 us; speedup vs baseline: 1.0397x; 1.0397x over previous
//
#include <hip/hip_runtime.h>
#include <hip/hip_bf16.h>
#include <math.h>

// Problem constants
#define BB 64
#define TT 4096
#define DD 256
#define UU 256
#define CHUNKS 8          // chunks per batch -> grid 512 blocks (all resident)
#define TCHUNK 512        // TT / CHUNKS
#define MT 64             // timestep tile per iteration
#define NTILES 8          // TCHUNK / MT
#define LDA 264           // padded LDS row stride in bf16 elems (+8 pad)

typedef __attribute__((ext_vector_type(8))) short bf16x8;
typedef __attribute__((ext_vector_type(4))) float f32x4;

static __device__ __forceinline__ short f2bf(float f){
  unsigned u = __float_as_uint(f);
  u = (u + 0x7fffu + ((u >> 16) & 1u)) >> 16;   // RNE
  return (short)u;
}

// packed fp32x2 -> bf16x2 (RNE); gfx950 has v_cvt_pk_bf16_f32
static __device__ __forceinline__ unsigned pk_bf16(float a, float b){
#if __has_builtin(__builtin_amdgcn_cvt_pk_bf16_f32)
  typedef __bf16 bf16v2 __attribute__((ext_vector_type(2)));
  bf16v2 r = __builtin_amdgcn_cvt_pk_bf16_f32(a, b);
  unsigned u; __builtin_memcpy(&u, &r, 4); return u;
#else
  unsigned ua = __float_as_uint(a), ub = __float_as_uint(b);
  ua = (ua + 0x7fffu + ((ua >> 16) & 1u)) >> 16;
  ub = (ub + 0x7fffu + ((ub >> 16) & 1u)) & 0xffff0000u;
  return ub | ua;
#endif
}

// workgroup barrier that does NOT drain vmcnt (keeps global prefetch in flight).
// LDS ops ordered via lgkmcnt(0); "memory" clobber = compiler-level fence.
static __device__ __forceinline__ void barrier_lds(){
  asm volatile("s_waitcnt lgkmcnt(0)\n\ts_barrier" ::: "memory");
}

// Kernel 0: W[d][u] fp32 -> pre-swizzled bf16 MFMA B-fragments.
// Frag f = wv*32 + nf*8 + kt; lane l (lo=l&15, quad=l>>4) holds
// u = wv*64+nf*16+lo, d = kt*32+quad*8+j (j=0..7), stored at Wf[(f*64+l)*8+j].
// K-loop load becomes one fully-coalesced 16B/lane transaction per frag.
__global__ void wfrag_kernel(const float* __restrict__ W, short* __restrict__ Wf){
  int g  = blockIdx.x*256 + threadIdx.x;   // 8192 threads = 128 frags * 64 lanes
  int l  = g & 63;
  int f  = g >> 6;
  int kt = f & 7, nf = (f >> 3) & 3, wv = f >> 5;
  int lo = l & 15, quad = l >> 4;
  int u  = wv*64 + nf*16 + lo;
  int d0 = kt*32 + quad*8;
  bf16x8 v;
  #pragma unroll
  for (int j=0;j<8;++j) v[j] = f2bf(W[(size_t)(d0+j)*UU + u]);
  *reinterpret_cast<bf16x8*>(&Wf[(size_t)g*8]) = v;
}

// Kernel 1: flash-style fused logits + online softmax + weighted sum (per chunk)
__global__ __launch_bounds__(256)
void attn_main_kernel(const float* __restrict__ X, const short* __restrict__ Wf,
                      const float* __restrict__ Wb, const float* __restrict__ Vw,
                      float* __restrict__ m_part, float* __restrict__ l_part,
                      float* __restrict__ ctx_part)
{
  __shared__ short a_tile[MT*LDA];   // 33792 B bf16 X tile (single buffer)
  __shared__ float s_part[4][MT];    // per-wave logit partials
  __shared__ float s_pw[4][MT];      // per-wave p broadcast (same-wave RAW)

  const int tid  = threadIdx.x;
  const int lane = tid & 63;
  const int wv   = tid >> 6;
  const int b      = blockIdx.x >> 3;
  const int cchunk = blockIdx.x & 7;
  const int lo   = lane & 15;
  const int quad = lane >> 4;
  const int u_base = wv*64 + lo;

  float wb_r[4], v_r[4];
  #pragma unroll
  for (int nf=0; nf<4; ++nf){
    wb_r[nf] = Wb[u_base + nf*16];
    v_r[nf]  = Vw[u_base + nf*16];
  }

  // per-wave coalesced fragment base: frags for this wave start at wv*32
  const short* wf_base = Wf + ((size_t)(wv*32*64 + lane))*8;

  float m_run = -INFINITY;
  float l_run = 0.f;
  float ctx   = 0.f;
  const size_t x_chunk = ((size_t)b*TT + (size_t)cchunk*TCHUNK) * DD;

  // prefetch tile 0 into registers
  float4 pf[16];
  #pragma unroll
  for (int p8=0; p8<8; ++p8){
    int e = p8*256 + tid, row = e >> 5, col = (e & 31)*8;
    const float4* src = reinterpret_cast<const float4*>(
        X + x_chunk + (size_t)row*DD + col);
    pf[2*p8]   = src[0];
    pf[2*p8+1] = src[1];
  }

  for (int tile=0; tile<NTILES; ++tile){
    barrier_lds();   // B1: prior ctx reads of a_tile complete everywhere

    // ---- pack prefetched tile -> LDS (pure VALU+DS, no global latency) ----
    #pragma unroll
    for (int p8=0; p8<8; ++p8){
      int e = p8*256 + tid, row = e >> 5, col = (e & 31)*8;
      int4 v;
      v.x = (int)pk_bf16(pf[2*p8].x,   pf[2*p8].y);
      v.y = (int)pk_bf16(pf[2*p8].z,   pf[2*p8].w);
      v.z = (int)pk_bf16(pf[2*p8+1].x, pf[2*p8+1].y);
      v.w = (int)pk_bf16(pf[2*p8+1].z, pf[2*p8+1].w);
      *reinterpret_cast<int4*>(&a_tile[row*LDA + col]) = v;
    }

    // ---- issue next tile's global loads (in flight across barriers) ----
    if (tile+1 < NTILES){
      #pragma unroll
      for (int p8=0; p8<8; ++p8){
        int e = p8*256 + tid, row = e >> 5, col = (e & 31)*8;
        const float4* src = reinterpret_cast<const float4*>(
            X + x_chunk + (size_t)((tile+1)*MT + row)*DD + col);
        pf[2*p8]   = src[0];
        pf[2*p8+1] = src[1];
      }
    }

    barrier_lds();   // B2: a_tile visible to all waves

    // ---- MFMA: score[64t x 64u] per wave, K=256 ----
    f32x4 acc[4][4];
    #pragma unroll
    for (int mf=0; mf<4; ++mf)
      #pragma unroll
      for (int nf=0; nf<4; ++nf)
        acc[mf][nf] = (f32x4){0.f,0.f,0.f,0.f};

    #pragma unroll
    for (int kt=0; kt<8; ++kt){
      const int k0 = kt*32 + quad*8;
      bf16x8 af[4];
      #pragma unroll
      for (int mf=0; mf<4; ++mf)
        af[mf] = *reinterpret_cast<const bf16x8*>(&a_tile[(mf*16 + lo)*LDA + k0]);
      #pragma unroll
      for (int nf=0; nf<4; ++nf){
        bf16x8 bfv = *reinterpret_cast<const bf16x8*>(wf_base + (nf*8 + kt)*512);
        #pragma unroll
        for (int mf=0; mf<4; ++mf)
          acc[mf][nf] = __builtin_amdgcn_mfma_f32_16x16x32_bf16(af[mf], bfv, acc[mf][nf], 0, 0, 0);
      }
    }

    // ---- epilogue: tanh, dot with V, reduce over this wave's 64 units ----
    // C/D layout: col(u)=lane&15, row(t)=quad*4+reg
    #pragma unroll
    for (int mf=0; mf<4; ++mf){
      #pragma unroll
      for (int r=0; r<4; ++r){
        float part = 0.f;
        #pragma unroll
        for (int nf=0; nf<4; ++nf){
          float s  = acc[mf][nf][r] + wb_r[nf];
          float e2 = __expf(2.f*s);
          float th = 1.f - 2.f/(e2 + 1.f);     // robust tanh
          part = fmaf(th, v_r[nf], part);
        }
        part += __shfl_xor(part, 1);
        part += __shfl_xor(part, 2);
        part += __shfl_xor(part, 4);
        part += __shfl_xor(part, 8);
        if (lo == 0) s_part[wv][mf*16 + quad*4 + r] = part;
      }
    }

    barrier_lds();   // B3: s_part visible

    // ---- per-wave redundant online softmax ----
    float lt = s_part[0][lane] + s_part[1][lane] + s_part[2][lane] + s_part[3][lane];
    float mx = lt;
    #pragma unroll
    for (int o=32; o; o>>=1) mx = fmaxf(mx, __shfl_xor(mx, o));
    float m_new = fmaxf(m_run, mx);
    float p = __expf(lt - m_new);
    float sum = p;
    #pragma unroll
    for (int o=32; o; o>>=1) sum += __shfl_xor(sum, o);
    float alpha = __expf(m_run - m_new);   // exp(-inf)=0 on first tile
    l_run = l_run * alpha + sum;
    m_run = m_new;
    s_pw[wv][lane] = p;

    // ---- ctx update from bf16 LDS tile: thread d=tid sums p[t]*Xbf[t][d] ----
    ctx *= alpha;
    #pragma unroll
    for (int t2=0; t2<MT; ++t2){
      float pt = s_pw[wv][t2];
      unsigned xb = (unsigned short)a_tile[t2*LDA + tid];
      ctx = fmaf(pt, __uint_as_float(xb << 16), ctx);
    }
  }

  const int pidx = blockIdx.x;
  if (tid == 0){ m_part[pidx] = m_run; l_part[pidx] = l_run; }
  ctx_part[(size_t)pidx*DD + tid] = ctx;
}

// Kernel 2: merge chunk partials per batch
__global__ void merge_kernel(const float* __restrict__ m_part, const float* __restrict__ l_part,
                             const float* __restrict__ ctx_part, float* __restrict__ out)
{
  int b = blockIdx.x;
  int d = threadIdx.x;
  float mg = -INFINITY;
  #pragma unroll
  for (int c=0; c<CHUNKS; ++c) mg = fmaxf(mg, m_part[b*CHUNKS+c]);
  float lg = 0.f, s = 0.f;
  #pragma unroll
  for (int c=0; c<CHUNKS; ++c){
    float w = __expf(m_part[b*CHUNKS+c] - mg);
    lg += l_part[b*CHUNKS+c] * w;
    s  += ctx_part[(size_t)(b*CHUNKS+c)*DD + d] * w;
  }
  out[b*DD + d] = s / lg;
}

extern "C" void kernel_launch(void* const* d_in, const int* in_sizes, int n_in,
                              void* d_out, int out_size, void* d_ws, size_t ws_size,
                              hipStream_t stream)
{
  const float* X  = (const float*)d_in[0];
  const float* Ww = (const float*)d_in[1];
  const float* Wb = (const float*)d_in[2];
  const float* Vw = (const float*)d_in[3];
  // V_b shifts all logits equally -> cancels in softmax; ignored.
  float* out = (float*)d_out;

  // workspace: Wf bf16 frags (128 KB) | m (512 f) | l (512 f) | ctx (512*256 f)
  short* Wf       = (short*)d_ws;
  float* m_part   = (float*)((char*)d_ws + (size_t)UU*DD*sizeof(short));
  float* l_part   = m_part + BB*CHUNKS;
  float* ctx_part = l_part + BB*CHUNKS;

  wfrag_kernel<<<32, 256, 0, stream>>>(Ww, Wf);
  attn_main_kernel<<<BB*CHUNKS, 256, 0, stream>>>(X, Wf, Wb, Vw, m_part, l_part, ctx_part);
  merge_kernel<<<BB, DD, 0, stream>>>(m_part, l_part, ctx_part, out);
}

// Round 4
// 429.706 us; speedup vs baseline: 1.1876x; 1.1423x over previous
//
#include <hip/hip_runtime.h>
#include <hip/hip_bf16.h>
#include <math.h>

// Problem constants
#define BB 64
#define TT 4096
#define DD 256
#define UU 256
#define MT 64             // timestep tile per block
#define NT (TT/MT)        // 64 tiles per batch
#define LDA 264           // padded LDS row stride in bf16 elems (+8 pad)

typedef __attribute__((ext_vector_type(8))) short bf16x8;
typedef __attribute__((ext_vector_type(4))) float f32x4;

static __device__ __forceinline__ short f2bf(float f){
  unsigned u = __float_as_uint(f);
  u = (u + 0x7fffu + ((u >> 16) & 1u)) >> 16;   // RNE
  return (short)u;
}

// packed fp32x2 -> bf16x2 (RNE); gfx950 has v_cvt_pk_bf16_f32
static __device__ __forceinline__ unsigned pk_bf16(float a, float b){
#if __has_builtin(__builtin_amdgcn_cvt_pk_bf16_f32)
  typedef __bf16 bf16v2 __attribute__((ext_vector_type(2)));
  bf16v2 r = __builtin_amdgcn_cvt_pk_bf16_f32(a, b);
  unsigned u; __builtin_memcpy(&u, &r, 4); return u;
#else
  unsigned ua = __float_as_uint(a), ub = __float_as_uint(b);
  ua = (ua + 0x7fffu + ((ua >> 16) & 1u)) >> 16;
  ub = (ub + 0x7fffu + ((ub >> 16) & 1u)) & 0xffff0000u;
  return ub | ua;
#endif
}

// Kernel 0: W[d][u] fp32 -> pre-swizzled bf16 MFMA B-fragments.
// Frag f = wv*32 + nf*8 + kt; lane l (lo=l&15, quad=l>>4) holds
// u = wv*64+nf*16+lo, d = kt*32+quad*8+j (j=0..7), at Wf[(f*64+l)*8+j].
__global__ void wfrag_kernel(const float* __restrict__ W, short* __restrict__ Wf){
  int g  = blockIdx.x*256 + threadIdx.x;   // 8192 threads = 128 frags * 64 lanes
  int l  = g & 63;
  int f  = g >> 6;
  int kt = f & 7, nf = (f >> 3) & 3, wv = f >> 5;
  int lo = l & 15, quad = l >> 4;
  int u  = wv*64 + nf*16 + lo;
  int d0 = kt*32 + quad*8;
  bf16x8 v;
  #pragma unroll
  for (int j=0;j<8;++j) v[j] = f2bf(W[(size_t)(d0+j)*UU + u]);
  *reinterpret_cast<bf16x8*>(&Wf[(size_t)g*8]) = v;
}

// Kernel 1: one independent 64-timestep tile per block. No serial tile loop,
// no online-softmax carried state — local softmax + materialized partials.
__global__ __launch_bounds__(256)
void attn_tile_kernel(const float* __restrict__ X, const short* __restrict__ Wf,
                      const float* __restrict__ Wb, const float* __restrict__ Vw,
                      float* __restrict__ m_part, float* __restrict__ l_part,
                      float* __restrict__ ctx_part)
{
  __shared__ short a_tile[MT*LDA];   // 33792 B bf16 X tile (MFMA A operand only)
  __shared__ float s_part[4][MT];    // per-wave logit partials
  __shared__ float s_pw[4][MT];      // per-wave p broadcast (same-wave RAW)
  __shared__ float s_red[8][264];    // ctx 8-group reduction (padded)

  const int tid  = threadIdx.x;
  const int lane = tid & 63;
  const int wv   = tid >> 6;
  const int lo   = lane & 15;
  const int quad = lane >> 4;
  const int u_base = wv*64 + lo;
  const int b  = blockIdx.x >> 6;        // batch
  const int tt = blockIdx.x & 63;        // tile within batch
  const size_t xbase = ((size_t)b*TT + (size_t)tt*MT)*DD;
  const int rgrp  = tid >> 5;            // 0..7: row group (8 rows each)
  const int cbase = (tid & 31)*8;        // 8-col chunk

  float wb_r[4], v_r[4];
  #pragma unroll
  for (int nf=0; nf<4; ++nf){
    wb_r[nf] = Wb[u_base + nf*16];
    v_r[nf]  = Vw[u_base + nf*16];
  }
  const short* wf_base = Wf + ((size_t)(wv*32*64 + lane))*8;

  // ---- load this block's 64x256 tile: thread holds rows {p8*8+rgrp}, cols cbase..+7
  float4 pf[16];
  #pragma unroll
  for (int p8=0; p8<8; ++p8){
    const float4* src = reinterpret_cast<const float4*>(
        X + xbase + (size_t)(p8*8 + rgrp)*DD + cbase);
    pf[2*p8]   = src[0];
    pf[2*p8+1] = src[1];
  }

  // ---- pack to bf16 LDS tile ----
  #pragma unroll
  for (int p8=0; p8<8; ++p8){
    int4 v;
    v.x = (int)pk_bf16(pf[2*p8].x,   pf[2*p8].y);
    v.y = (int)pk_bf16(pf[2*p8].z,   pf[2*p8].w);
    v.z = (int)pk_bf16(pf[2*p8+1].x, pf[2*p8+1].y);
    v.w = (int)pk_bf16(pf[2*p8+1].z, pf[2*p8+1].w);
    *reinterpret_cast<int4*>(&a_tile[(p8*8 + rgrp)*LDA + cbase]) = v;
  }
  __syncthreads();

  // ---- MFMA: score[64t x 64u] per wave, K=256 ----
  f32x4 acc[4][4];
  #pragma unroll
  for (int mf=0; mf<4; ++mf)
    #pragma unroll
    for (int nf=0; nf<4; ++nf)
      acc[mf][nf] = (f32x4){0.f,0.f,0.f,0.f};

  #pragma unroll
  for (int kt=0; kt<8; ++kt){
    const int k0 = kt*32 + quad*8;
    bf16x8 af[4];
    #pragma unroll
    for (int mf=0; mf<4; ++mf)
      af[mf] = *reinterpret_cast<const bf16x8*>(&a_tile[(mf*16 + lo)*LDA + k0]);
    #pragma unroll
    for (int nf=0; nf<4; ++nf){
      bf16x8 bfv = *reinterpret_cast<const bf16x8*>(wf_base + (nf*8 + kt)*512);
      #pragma unroll
      for (int mf=0; mf<4; ++mf)
        acc[mf][nf] = __builtin_amdgcn_mfma_f32_16x16x32_bf16(af[mf], bfv, acc[mf][nf], 0, 0, 0);
    }
  }

  // ---- epilogue: tanh, dot with V, reduce over this wave's 64 units ----
  // C/D layout: col(u)=lane&15, row(t)=quad*4+reg
  #pragma unroll
  for (int mf=0; mf<4; ++mf){
    #pragma unroll
    for (int r=0; r<4; ++r){
      float part = 0.f;
      #pragma unroll
      for (int nf=0; nf<4; ++nf){
        float s  = acc[mf][nf][r] + wb_r[nf];
        float e2 = __expf(2.f*s);
        float th = 1.f - 2.f/(e2 + 1.f);     // robust tanh
        part = fmaf(th, v_r[nf], part);
      }
      part += __shfl_xor(part, 1);
      part += __shfl_xor(part, 2);
      part += __shfl_xor(part, 4);
      part += __shfl_xor(part, 8);
      if (lo == 0) s_part[wv][mf*16 + quad*4 + r] = part;
    }
  }
  __syncthreads();

  // ---- per-wave redundant local softmax over the 64 tile logits ----
  float lt = s_part[0][lane] + s_part[1][lane] + s_part[2][lane] + s_part[3][lane];
  float mx = lt;
  #pragma unroll
  for (int o=32; o; o>>=1) mx = fmaxf(mx, __shfl_xor(mx, o));
  float p = __expf(lt - mx);
  float sum = p;
  #pragma unroll
  for (int o=32; o; o>>=1) sum += __shfl_xor(sum, o);
  s_pw[wv][lane] = p;                    // same-wave producer/consumer

  // ---- ctx partial from fp32 registers (no LDS tile re-walk) ----
  float cp[8] = {0.f,0.f,0.f,0.f,0.f,0.f,0.f,0.f};
  #pragma unroll
  for (int p8=0; p8<8; ++p8){
    float pr = s_pw[wv][p8*8 + rgrp];    // p for this thread's row
    cp[0] = fmaf(pr, pf[2*p8].x,   cp[0]);
    cp[1] = fmaf(pr, pf[2*p8].y,   cp[1]);
    cp[2] = fmaf(pr, pf[2*p8].z,   cp[2]);
    cp[3] = fmaf(pr, pf[2*p8].w,   cp[3]);
    cp[4] = fmaf(pr, pf[2*p8+1].x, cp[4]);
    cp[5] = fmaf(pr, pf[2*p8+1].y, cp[5]);
    cp[6] = fmaf(pr, pf[2*p8+1].z, cp[6]);
    cp[7] = fmaf(pr, pf[2*p8+1].w, cp[7]);
  }
  *reinterpret_cast<float4*>(&s_red[rgrp][cbase])   = (float4){cp[0],cp[1],cp[2],cp[3]};
  *reinterpret_cast<float4*>(&s_red[rgrp][cbase+4]) = (float4){cp[4],cp[5],cp[6],cp[7]};
  __syncthreads();

  float ctx = 0.f;
  #pragma unroll
  for (int g=0; g<8; ++g) ctx += s_red[g][tid];

  if (tid == 0){ m_part[blockIdx.x] = mx; l_part[blockIdx.x] = sum; }
  ctx_part[(size_t)blockIdx.x*DD + tid] = ctx;
}

// Kernel 2: merge the 64 tile partials per batch with max-rescaling
__global__ void merge_kernel(const float* __restrict__ m_part, const float* __restrict__ l_part,
                             const float* __restrict__ ctx_part, float* __restrict__ out)
{
  int b = blockIdx.x;
  int d = threadIdx.x;
  float mg = -INFINITY;
  #pragma unroll 8
  for (int i=0; i<NT; ++i) mg = fmaxf(mg, m_part[b*NT+i]);
  float lg = 0.f, s = 0.f;
  #pragma unroll 8
  for (int i=0; i<NT; ++i){
    float w = __expf(m_part[b*NT+i] - mg);
    lg += l_part[b*NT+i] * w;
    s  += ctx_part[(size_t)(b*NT+i)*DD + d] * w;
  }
  out[b*DD + d] = s / lg;
}

extern "C" void kernel_launch(void* const* d_in, const int* in_sizes, int n_in,
                              void* d_out, int out_size, void* d_ws, size_t ws_size,
                              hipStream_t stream)
{
  const float* X  = (const float*)d_in[0];
  const float* Ww = (const float*)d_in[1];
  const float* Wb = (const float*)d_in[2];
  const float* Vw = (const float*)d_in[3];
  // V_b shifts all logits equally -> cancels in softmax; ignored.
  float* out = (float*)d_out;

  // workspace: Wf bf16 frags (128 KB) | m (4096 f) | l (4096 f) | ctx (4096*256 f)
  short* Wf       = (short*)d_ws;
  float* m_part   = (float*)((char*)d_ws + (size_t)UU*DD*sizeof(short));
  float* l_part   = m_part + BB*NT;
  float* ctx_part = l_part + BB*NT;

  wfrag_kernel<<<32, 256, 0, stream>>>(Ww, Wf);
  attn_tile_kernel<<<BB*NT, 256, 0, stream>>>(X, Wf, Wb, Vw, m_part, l_part, ctx_part);
  merge_kernel<<<BB, DD, 0, stream>>>(m_part, l_part, ctx_part, out);
}

// Round 5
// 420.414 us; speedup vs baseline: 1.2139x; 1.0221x over previous
//
#include <hip/hip_runtime.h>
#include <hip/hip_bf16.h>
#include <math.h>

// Problem constants
#define BB 64
#define TT 4096
#define DD 256
#define UU 256
#define MT 32             // timestep tile per block
#define NT (TT/MT)        // 128 tiles per batch
#define LDA 264           // padded LDS row stride in bf16 elems (+8 pad)

typedef __attribute__((ext_vector_type(8))) short bf16x8;
typedef __attribute__((ext_vector_type(4))) float f32x4;

static __device__ __forceinline__ short f2bf(float f){
  unsigned u = __float_as_uint(f);
  u = (u + 0x7fffu + ((u >> 16) & 1u)) >> 16;   // RNE
  return (short)u;
}

// packed fp32x2 -> bf16x2 (RNE); gfx950 has v_cvt_pk_bf16_f32
static __device__ __forceinline__ unsigned pk_bf16(float a, float b){
#if __has_builtin(__builtin_amdgcn_cvt_pk_bf16_f32)
  typedef __bf16 bf16v2 __attribute__((ext_vector_type(2)));
  bf16v2 r = __builtin_amdgcn_cvt_pk_bf16_f32(a, b);
  unsigned u; __builtin_memcpy(&u, &r, 4); return u;
#else
  unsigned ua = __float_as_uint(a), ub = __float_as_uint(b);
  ua = (ua + 0x7fffu + ((ua >> 16) & 1u)) >> 16;
  ub = (ub + 0x7fffu + ((ub >> 16) & 1u)) & 0xffff0000u;
  return ub | ua;
#endif
}

// Kernel 0: W[d][u] fp32 -> pre-swizzled bf16 MFMA B-fragments.
// Frag f = wv*32 + nf*8 + kt; lane l (lo=l&15, quad=l>>4) holds
// u = wv*64+nf*16+lo, d = kt*32+quad*8+j (j=0..7), at Wf[(f*64+l)*8+j].
__global__ void wfrag_kernel(const float* __restrict__ W, short* __restrict__ Wf){
  int g  = blockIdx.x*256 + threadIdx.x;   // 8192 threads = 128 frags * 64 lanes
  int l  = g & 63;
  int f  = g >> 6;
  int kt = f & 7, nf = (f >> 3) & 3, wv = f >> 5;
  int lo = l & 15, quad = l >> 4;
  int u  = wv*64 + nf*16 + lo;
  int d0 = kt*32 + quad*8;
  bf16x8 v;
  #pragma unroll
  for (int j=0;j<8;++j) v[j] = f2bf(W[(size_t)(d0+j)*UU + u]);
  *reinterpret_cast<bf16x8*>(&Wf[(size_t)g*8]) = v;
}

// Kernel 1: one independent 32-timestep tile per block (8192 blocks).
// Small LDS + small VGPR -> 5+ blocks/CU resident: latency hidden by churn.
__global__ __launch_bounds__(256, 5)
void attn_tile_kernel(const float* __restrict__ X, const short* __restrict__ Wf,
                      const float* __restrict__ Wb, const float* __restrict__ Vw,
                      float* __restrict__ m_part, float* __restrict__ l_part,
                      float* __restrict__ ctx_part)
{
  __shared__ short a_tile[MT*LDA];   // 16896 B bf16 X tile
  __shared__ float s_part[4][MT];    // per-wave logit partials
  __shared__ float s_pw[4][MT];      // per-wave p broadcast (same-wave RAW)
  __shared__ float s_red[8][264];    // ctx 8-group reduction (padded)

  const int tid  = threadIdx.x;
  const int lane = tid & 63;
  const int wv   = tid >> 6;
  const int lo   = lane & 15;
  const int quad = lane >> 4;
  const int u_base = wv*64 + lo;
  const int b  = blockIdx.x >> 7;        // batch
  const int tt = blockIdx.x & 127;       // tile within batch
  const size_t xbase = ((size_t)b*TT + (size_t)tt*MT)*DD;
  const int rgrp  = tid >> 5;            // 0..7: row group (4 rows each)
  const int cbase = (tid & 31)*8;        // 8-col chunk

  float wb_r[4], v_r[4];
  #pragma unroll
  for (int nf=0; nf<4; ++nf){
    wb_r[nf] = Wb[u_base + nf*16];
    v_r[nf]  = Vw[u_base + nf*16];
  }
  const short* wf_base = Wf + ((size_t)(wv*32*64 + lane))*8;

  // ---- load 32x256 tile, pack to bf16 LDS; rows {p8*8+rgrp}, cols cbase..+7
  #pragma unroll
  for (int p8=0; p8<4; ++p8){
    const float4* src = reinterpret_cast<const float4*>(
        X + xbase + (size_t)(p8*8 + rgrp)*DD + cbase);
    float4 x0 = src[0];
    float4 x1 = src[1];
    int4 v;
    v.x = (int)pk_bf16(x0.x, x0.y);
    v.y = (int)pk_bf16(x0.z, x0.w);
    v.z = (int)pk_bf16(x1.x, x1.y);
    v.w = (int)pk_bf16(x1.z, x1.w);
    *reinterpret_cast<int4*>(&a_tile[(p8*8 + rgrp)*LDA + cbase]) = v;
  }
  __syncthreads();

  // ---- MFMA: score[32t x 64u] per wave, K=256 ----
  f32x4 acc[2][4];
  #pragma unroll
  for (int mf=0; mf<2; ++mf)
    #pragma unroll
    for (int nf=0; nf<4; ++nf)
      acc[mf][nf] = (f32x4){0.f,0.f,0.f,0.f};

  #pragma unroll
  for (int kt=0; kt<8; ++kt){
    const int k0 = kt*32 + quad*8;
    bf16x8 af[2];
    #pragma unroll
    for (int mf=0; mf<2; ++mf)
      af[mf] = *reinterpret_cast<const bf16x8*>(&a_tile[(mf*16 + lo)*LDA + k0]);
    #pragma unroll
    for (int nf=0; nf<4; ++nf){
      bf16x8 bfv = *reinterpret_cast<const bf16x8*>(wf_base + (nf*8 + kt)*512);
      #pragma unroll
      for (int mf=0; mf<2; ++mf)
        acc[mf][nf] = __builtin_amdgcn_mfma_f32_16x16x32_bf16(af[mf], bfv, acc[mf][nf], 0, 0, 0);
    }
  }

  // ---- epilogue: tanh, dot with V, reduce over this wave's 64 units ----
  // C/D layout: col(u)=lane&15, row(t)=quad*4+reg
  #pragma unroll
  for (int mf=0; mf<2; ++mf){
    #pragma unroll
    for (int r=0; r<4; ++r){
      float part = 0.f;
      #pragma unroll
      for (int nf=0; nf<4; ++nf){
        float s  = acc[mf][nf][r] + wb_r[nf];
        float e2 = __expf(2.f*s);
        float th = 1.f - 2.f/(e2 + 1.f);     // robust tanh
        part = fmaf(th, v_r[nf], part);
      }
      part += __shfl_xor(part, 1);
      part += __shfl_xor(part, 2);
      part += __shfl_xor(part, 4);
      part += __shfl_xor(part, 8);
      if (lo == 0) s_part[wv][mf*16 + quad*4 + r] = part;
    }
  }
  __syncthreads();

  // ---- per-wave redundant local softmax over the 32 tile logits ----
  const int li = lane & 31;
  float lt = s_part[0][li] + s_part[1][li] + s_part[2][li] + s_part[3][li];
  float mx = lt;
  #pragma unroll
  for (int o=16; o; o>>=1) mx = fmaxf(mx, __shfl_xor(mx, o));
  float p = __expf(lt - mx);
  float sum = p;
  #pragma unroll
  for (int o=16; o; o>>=1) sum += __shfl_xor(sum, o);
  s_pw[wv][li] = p;                    // same-wave producer/consumer (dup-safe)

  // ---- ctx partial from the bf16 LDS tile (rows p8*8+rgrp, cols cbase..+7) ----
  float cp[8] = {0.f,0.f,0.f,0.f,0.f,0.f,0.f,0.f};
  #pragma unroll
  for (int p8=0; p8<4; ++p8){
    float pr = s_pw[wv][p8*8 + rgrp];
    bf16x8 xv = *reinterpret_cast<const bf16x8*>(&a_tile[(p8*8 + rgrp)*LDA + cbase]);
    #pragma unroll
    for (int j=0; j<8; ++j){
      float x = __uint_as_float(((unsigned)(unsigned short)xv[j]) << 16);
      cp[j] = fmaf(pr, x, cp[j]);
    }
  }
  *reinterpret_cast<float4*>(&s_red[rgrp][cbase])   = (float4){cp[0],cp[1],cp[2],cp[3]};
  *reinterpret_cast<float4*>(&s_red[rgrp][cbase+4]) = (float4){cp[4],cp[5],cp[6],cp[7]};
  __syncthreads();

  float ctx = 0.f;
  #pragma unroll
  for (int g=0; g<8; ++g) ctx += s_red[g][tid];

  if (tid == 0){ m_part[blockIdx.x] = mx; l_part[blockIdx.x] = sum; }
  ctx_part[(size_t)blockIdx.x*DD + tid] = ctx;
}

// Kernel 2: merge the 128 tile partials per batch with max-rescaling.
// 64 blocks x 1024 threads: thread (g=tid>>8, d=tid&255) sums 32 tiles.
__global__ __launch_bounds__(1024)
void merge_kernel(const float* __restrict__ m_part, const float* __restrict__ l_part,
                  const float* __restrict__ ctx_part, float* __restrict__ out)
{
  __shared__ float s_sum[4][256];
  const int b = blockIdx.x;
  const int g = threadIdx.x >> 8;
  const int d = threadIdx.x & 255;

  float mg = -INFINITY;
  #pragma unroll 16
  for (int i=0; i<NT; ++i) mg = fmaxf(mg, m_part[b*NT+i]);
  float lg = 0.f;
  #pragma unroll 16
  for (int i=0; i<NT; ++i) lg += l_part[b*NT+i] * __expf(m_part[b*NT+i] - mg);

  float s = 0.f;
  #pragma unroll 8
  for (int i=0; i<32; ++i){
    int t = g*32 + i;
    float w = __expf(m_part[b*NT+t] - mg);
    s = fmaf(w, ctx_part[(size_t)(b*NT+t)*DD + d], s);
  }
  s_sum[g][d] = s;
  __syncthreads();
  if (threadIdx.x < 256){
    float tot = s_sum[0][threadIdx.x] + s_sum[1][threadIdx.x]
              + s_sum[2][threadIdx.x] + s_sum[3][threadIdx.x];
    out[b*DD + threadIdx.x] = tot / lg;
  }
}

extern "C" void kernel_launch(void* const* d_in, const int* in_sizes, int n_in,
                              void* d_out, int out_size, void* d_ws, size_t ws_size,
                              hipStream_t stream)
{
  const float* X  = (const float*)d_in[0];
  const float* Ww = (const float*)d_in[1];
  const float* Wb = (const float*)d_in[2];
  const float* Vw = (const float*)d_in[3];
  // V_b shifts all logits equally -> cancels in softmax; ignored.
  float* out = (float*)d_out;

  // workspace: Wf bf16 frags (128 KB) | m (8192 f) | l (8192 f) | ctx (8192*256 f)
  short* Wf       = (short*)d_ws;
  float* m_part   = (float*)((char*)d_ws + (size_t)UU*DD*sizeof(short));
  float* l_part   = m_part + BB*NT;
  float* ctx_part = l_part + BB*NT;

  wfrag_kernel<<<32, 256, 0, stream>>>(Ww, Wf);
  attn_tile_kernel<<<BB*NT, 256, 0, stream>>>(X, Wf, Wb, Vw, m_part, l_part, ctx_part);
  merge_kernel<<<BB, 1024, 0, stream>>>(m_part, l_part, ctx_part, out);
}